// Round 1
// baseline (281.552 us; speedup 1.0000x reference)
//
#include <hip/hip_runtime.h>

// Modulated deformable conv 3x3, in_ch=out_ch=1, stride=1, pad=1, dil=1.
// B=8, H=W=512 (hardcoded from setup_inputs).
// d_in order: depth, mask(weight), offset, w, b.

#define KK 9
#define PAD 1

__device__ __forceinline__ float bilin(const float* __restrict__ img,
                                       int H, int W, float y, float x) {
    float y0f = floorf(y);
    float x0f = floorf(x);
    int y0 = (int)y0f;
    int x0 = (int)x0f;
    float wy = y - y0f;
    float wx = x - x0f;
    int y1 = y0 + 1;
    int x1 = x0 + 1;

    bool y0i = (y0 >= 0) & (y0 < H);
    bool y1i = (y1 >= 0) & (y1 < H);
    bool x0i = (x0 >= 0) & (x0 < W);
    bool x1i = (x1 >= 0) & (x1 < W);

    int y0c = min(max(y0, 0), H - 1);
    int y1c = min(max(y1, 0), H - 1);
    int x0c = min(max(x0, 0), W - 1);
    int x1c = min(max(x1, 0), W - 1);

    const float* r0 = img + (long)y0c * W;
    const float* r1 = img + (long)y1c * W;

    float v00 = (y0i & x0i) ? r0[x0c] : 0.0f;
    float v01 = (y0i & x1i) ? r0[x1c] : 0.0f;
    float v10 = (y1i & x0i) ? r1[x0c] : 0.0f;
    float v11 = (y1i & x1i) ? r1[x1c] : 0.0f;

    float omwy = 1.0f - wy;
    float omwx = 1.0f - wx;
    return v00 * omwy * omwx + v01 * omwy * wx + v10 * wy * omwx + v11 * wy * wx;
}

__global__ __launch_bounds__(256) void dcn_kernel(
    const float* __restrict__ depth,
    const float* __restrict__ mask,
    const float* __restrict__ offset,
    const float* __restrict__ w9,
    const float* __restrict__ bias,
    float* __restrict__ out,
    int H, int W) {
    const int HW = H * W;
    const int p = blockIdx.x * blockDim.x + threadIdx.x;   // pixel index in HW
    if (p >= HW) return;
    const int b = blockIdx.y;

    const int y = p / W;   // W=512 -> compiler uses shifts
    const int x = p - y * W;

    const float* __restrict__ img = depth + (long)b * HW;
    const float* __restrict__ msk = mask + (long)b * KK * HW + p;
    const float* __restrict__ off = offset + (long)b * 2 * KK * HW + p;

    float acc = bias[0];

    #pragma unroll
    for (int k = 0; k < KK; ++k) {
        const int ky = k / 3;
        const int kx = k - ky * 3;
        const float dy = off[(long)(2 * k) * HW];
        const float dx = off[(long)(2 * k + 1) * HW];
        const float m  = msk[(long)k * HW];
        const float sy = (float)(y - PAD + ky) + dy;
        const float sx = (float)(x - PAD + kx) + dx;
        acc += bilin(img, H, W, sy, sx) * m * w9[k];
    }

    out[(long)b * HW + p] = acc;
}

extern "C" void kernel_launch(void* const* d_in, const int* in_sizes, int n_in,
                              void* d_out, int out_size, void* d_ws, size_t ws_size,
                              hipStream_t stream) {
    const float* depth  = (const float*)d_in[0];
    const float* mask   = (const float*)d_in[1];   // reference's "weight" arg = modulation mask
    const float* offset = (const float*)d_in[2];
    const float* w9     = (const float*)d_in[3];
    const float* bias   = (const float*)d_in[4];
    float* out = (float*)d_out;

    const int H = 512, W = 512;
    const int HW = H * W;
    const int B = in_sizes[0] / HW;   // = 8

    dim3 block(256);
    dim3 grid((HW + 255) / 256, B);
    dcn_kernel<<<grid, block, 0, stream>>>(depth, mask, offset, w9, bias, out, H, W);
}